// Round 2
// baseline (41824.725 us; speedup 1.0000x reference)
//
#include <hip/hip_runtime.h>

// LSTM: S=4096, I=64, H=1024, O=1, fp32.
// Strategy: single persistent cooperative kernel. 256 blocks x 256 threads.
//   block b, wave w (0..3): owns h-index j = 4b+w
//   lane group g = lane>>4 (4 groups): gate q = g, row r = q*1024 + j
//   sub-lane sl = lane&15: holds W_hh[r][4*sl + 64*c + i], c=0..15, i=0..3 (64 VGPRs)
//   plus W_ih[r][4*sl .. +4] (input contribution fused as 64-wide extension of h)
// Per step: stage h (global->LDS, coalesced) -> 68 reg-resident FMAs/lane ->
//   4-stage xor-shuffle reduce over 16 lanes -> gather 4 gates -> activations ->
//   c,h update (replicated per-lane) -> lane0 writes h -> grid barrier.
// h double-buffered in ws; barrier = monotonic counter (release add / acquire spin).

#define SEQ_LEN 4096
#define HID 1024
#define NBLK 256
#define TPB 256

__device__ __forceinline__ float fast_sigmoid(float x) {
    // 1/(1+2^(-x*log2e)); v_exp_f32 + v_rcp_f32, ~1ulp each. |x| bounded (~10s).
    return __builtin_amdgcn_rcpf(1.0f + __builtin_amdgcn_exp2f(-1.4426950408889634f * x));
}
__device__ __forceinline__ float fast_tanh(float x) {
    // 1 - 2/(1+e^(2x))
    return fmaf(-2.0f, __builtin_amdgcn_rcpf(1.0f + __builtin_amdgcn_exp2f(2.8853900817779268f * x)), 1.0f);
}

// ws layout (floats): [0..1023] hbuf0, [1024..2047] hbuf1, [2048] counter(u32)
__global__ void lstm_init_kernel(float* ws) {
    int t = threadIdx.x;
    ((float4*)ws)[t] = make_float4(0.f, 0.f, 0.f, 0.f);   // hbuf0 = h_0 = 0
    if (t == 0) *((unsigned*)(ws + 2 * HID)) = 0u;        // barrier counter
}

__global__ __launch_bounds__(TPB, 1) void lstm_persistent_kernel(
    const float* __restrict__ input,   // [4096][64]
    const float* __restrict__ W_ih,    // [4096][64]
    const float* __restrict__ W_hh,    // [4096][1024]
    const float* __restrict__ b_ih,    // [4096]
    const float* __restrict__ b_hh,    // [4096]
    const float* __restrict__ W_lin,   // [1][1024]
    const float* __restrict__ b_lin,   // [1]
    float* __restrict__ out,           // [1]
    float* __restrict__ ws)
{
    const int t   = threadIdx.x;
    const int b   = blockIdx.x;
    const int w   = t >> 6;      // wave in block
    const int l   = t & 63;      // lane
    const int grp = l >> 4;      // gate q
    const int sl  = l & 15;      // sub-lane within gate group
    const int j   = 4 * b + w;   // owned h index
    const int row = grp * HID + j;

    float* hbuf0 = ws;
    float* hbuf1 = ws + HID;
    unsigned* counter = (unsigned*)(ws + 2 * HID);

    __shared__ float hs[HID + 64];   // h (1024) then x_s (64)
    __shared__ float red[4];
    float4* hs4 = (float4*)hs;

    // Register-resident weights (persist across all 4096 steps)
    float4 wreg[16];
    {
        const float4* Whh4 = (const float4*)(W_hh + (size_t)row * HID);
        #pragma unroll
        for (int c = 0; c < 16; ++c) wreg[c] = Whh4[sl + 16 * c];
    }
    const float4 wih = ((const float4*)(W_ih + (size_t)row * 64))[sl];

    // biases for this wave's 4 gate rows (gate order i,f,g,o)
    float bias[4];
    #pragma unroll
    for (int q = 0; q < 4; ++q) bias[q] = b_ih[q * HID + j] + b_hh[q * HID + j];

    const float4* xin4 = (const float4*)input;

    float c_state = 0.0f;

    for (int s = 0; s < SEQ_LEN; ++s) {
        const float* hread = (s & 1) ? hbuf1 : hbuf0;
        float* hwrite      = (s & 1) ? hbuf0 : hbuf1;

        // stage h_s and x_s into LDS (coalesced 4KB + 256B)
        float4 hv = ((const float4*)hread)[t];
        hs4[t] = hv;
        if (t < 16) hs4[256 + t] = xin4[s * 16 + t];
        __syncthreads();

        // 64 FMAs vs W_hh + 4 vs W_ih, all weights in VGPRs.
        // LDS read hs4[16c+sl]: element 64c+4sl -> 2 lanes/bank (free), 4-way
        // broadcast across gate groups (free).
        float acc = 0.0f;
        #pragma unroll
        for (int c = 0; c < 16; ++c) {
            float4 h4 = hs4[16 * c + sl];
            acc = fmaf(wreg[c].x, h4.x, acc);
            acc = fmaf(wreg[c].y, h4.y, acc);
            acc = fmaf(wreg[c].z, h4.z, acc);
            acc = fmaf(wreg[c].w, h4.w, acc);
        }
        {
            float4 x4 = hs4[256 + sl];
            acc = fmaf(wih.x, x4.x, acc);
            acc = fmaf(wih.y, x4.y, acc);
            acc = fmaf(wih.z, x4.z, acc);
            acc = fmaf(wih.w, x4.w, acc);
        }

        // reduce across the 16 lanes of the gate group
        acc += __shfl_xor(acc, 1);
        acc += __shfl_xor(acc, 2);
        acc += __shfl_xor(acc, 4);
        acc += __shfl_xor(acc, 8);

        // gather the 4 gate preactivations (uniform within each group)
        float gi = __shfl(acc, 0)  + bias[0];
        float gf = __shfl(acc, 16) + bias[1];
        float gg = __shfl(acc, 32) + bias[2];
        float go = __shfl(acc, 48) + bias[3];

        float ig = fast_sigmoid(gi);
        float fg = fast_sigmoid(gf);
        float cg = fast_tanh(gg);
        float og = fast_sigmoid(go);
        c_state  = fmaf(fg, c_state, ig * cg);
        float hn = og * fast_tanh(c_state);

        if (l == 0) hwrite[j] = hn;   // one float per wave
        __syncthreads();              // all stores drained (vmcnt(0) before s_barrier)

        // grid barrier: monotonic counter, device scope (cross-XCD safe).
        // RELEASE on the add publishes this block's h-write; ACQUIRE on the
        // spin load (the one that observes target) pulls in all publishes.
        if (t == 0) {
            __hip_atomic_fetch_add(counter, 1u, __ATOMIC_RELEASE, __HIP_MEMORY_SCOPE_AGENT);
            const unsigned target = (unsigned)(s + 1) * (unsigned)NBLK;
            while (__hip_atomic_load(counter, __ATOMIC_ACQUIRE, __HIP_MEMORY_SCOPE_AGENT) < target)
                __builtin_amdgcn_s_sleep(1);
        }
        __syncthreads();
    }

    // final projection: out = h_4096 . W_lin + b_lin  (h_4096 lives in hbuf0, 4096 even)
    if (b == 0) {
        float4 hv = ((const float4*)hbuf0)[t];
        float4 wl = ((const float4*)W_lin)[t];
        float p = hv.x * wl.x + hv.y * wl.y + hv.z * wl.z + hv.w * wl.w;
        #pragma unroll
        for (int m = 32; m >= 1; m >>= 1) p += __shfl_xor(p, m);
        if (l == 0) red[w] = p;
        __syncthreads();
        if (t == 0) out[0] = red[0] + red[1] + red[2] + red[3] + b_lin[0];
    }
}

extern "C" void kernel_launch(void* const* d_in, const int* in_sizes, int n_in,
                              void* d_out, int out_size, void* d_ws, size_t ws_size,
                              hipStream_t stream) {
    const float* input = (const float*)d_in[0];
    const float* W_ih  = (const float*)d_in[1];
    const float* W_hh  = (const float*)d_in[2];
    const float* b_ih  = (const float*)d_in[3];
    const float* b_hh  = (const float*)d_in[4];
    const float* W_lin = (const float*)d_in[5];
    const float* b_lin = (const float*)d_in[6];
    float* out = (float*)d_out;
    float* ws  = (float*)d_ws;

    hipLaunchKernelGGL(lstm_init_kernel, dim3(1), dim3(256), 0, stream, ws);

    void* args[] = { (void*)&input, (void*)&W_ih, (void*)&W_hh, (void*)&b_ih,
                     (void*)&b_hh, (void*)&W_lin, (void*)&b_lin, (void*)&out, (void*)&ws };
    (void)hipLaunchCooperativeKernel((void*)lstm_persistent_kernel, dim3(NBLK), dim3(TPB),
                                     args, 0, stream);
}

// Round 3
// 37204.282 us; speedup vs baseline: 1.1242x; 1.1242x over previous
//
#include <hip/hip_runtime.h>

// LSTM: S=4096, I=64, H=1024, O=1, fp32.
// Persistent cooperative kernel, 256 blocks x 256 threads.
//   block b, wave w (0..3): owns h-index j = 4b+w
//   lane group grp = lane>>4: gate q = grp, row r = q*1024 + j
//   sub-lane sl = lane&15: holds W_hh[r][64c+4sl .. +3] c=0..15 (64 regs)
//     + W_ih[r][4sl .. +3] (4 regs), PINNED in VGPRs via asm (round-2 showed
//     VGPR_Count=52: LLVM remat'd the loads into the loop -> 17.8 MB/step L2/L3 re-read).
// Barrier: per-block monotonic flags (release store) + all-poll-all (relaxed
//   coalesced loads) + one device acquire fence. No shared-counter RMW serialization.

#define SEQ_LEN 4096
#define HID 1024
#define NBLK 256
#define TPB 256

__device__ __forceinline__ float fast_sigmoid(float x) {
    return __builtin_amdgcn_rcpf(1.0f + __builtin_amdgcn_exp2f(-1.4426950408889634f * x));
}
__device__ __forceinline__ float fast_tanh(float x) {
    return fmaf(-2.0f, __builtin_amdgcn_rcpf(1.0f + __builtin_amdgcn_exp2f(2.8853900817779268f * x)), 1.0f);
}
__device__ __forceinline__ unsigned umin4(unsigned a, unsigned b, unsigned c, unsigned d) {
    unsigned x = a < b ? a : b;
    unsigned y = c < d ? c : d;
    return x < y ? x : y;
}

// ws layout (floats): [0..1023] hbuf0, [1024..2047] hbuf1, then u32 flags[256]
__global__ void lstm_init_kernel(float* ws) {
    int t = threadIdx.x;
    ((float4*)ws)[t] = make_float4(0.f, 0.f, 0.f, 0.f);   // hbuf0 = h_0 = 0
    ((unsigned*)(ws + 2 * HID))[t] = 0u;                  // flags = 0
}

__global__ __launch_bounds__(TPB, 1) void lstm_persistent_kernel(
    const float* __restrict__ input,   // [4096][64]
    const float* __restrict__ W_ih,    // [4096][64]
    const float* __restrict__ W_hh,    // [4096][1024]
    const float* __restrict__ b_ih,    // [4096]
    const float* __restrict__ b_hh,    // [4096]
    const float* __restrict__ W_lin,   // [1][1024]
    const float* __restrict__ b_lin,   // [1]
    float* __restrict__ out,           // [1]
    float* __restrict__ ws)
{
    const int t   = threadIdx.x;
    const int b   = blockIdx.x;
    const int w   = t >> 6;      // wave in block
    const int l   = t & 63;      // lane
    const int grp = l >> 4;      // gate q
    const int sl  = l & 15;      // sub-lane within gate group
    const int j   = 4 * b + w;   // owned h index
    const int row = grp * HID + j;

    float* hbuf0 = ws;
    float* hbuf1 = ws + HID;
    unsigned* flags = (unsigned*)(ws + 2 * HID);

    __shared__ float hs[HID + 64];   // h (1024) then x_s (64)
    __shared__ float red[4];
    float4* hs4 = (float4*)hs;

    // ---- preload weights and PIN them in VGPRs ----
    float wr[68];
    {
        const float4* Whh4 = (const float4*)(W_hh + (size_t)row * HID);
        #pragma unroll
        for (int c = 0; c < 16; ++c) {
            float4 v = Whh4[sl + 16 * c];
            wr[4 * c + 0] = v.x; wr[4 * c + 1] = v.y;
            wr[4 * c + 2] = v.z; wr[4 * c + 3] = v.w;
        }
        float4 vi = ((const float4*)(W_ih + (size_t)row * 64))[sl];
        wr[64] = vi.x; wr[65] = vi.y; wr[66] = vi.z; wr[67] = vi.w;
    }
    #pragma unroll
    for (int k = 0; k < 68; ++k) asm volatile("" : "+v"(wr[k]));

    float bias[4];
    #pragma unroll
    for (int q = 0; q < 4; ++q) bias[q] = b_ih[q * HID + j] + b_hh[q * HID + j];
    #pragma unroll
    for (int q = 0; q < 4; ++q) asm volatile("" : "+v"(bias[q]));

    const float4* xin4 = (const float4*)input;

    float c_state = 0.0f;

    for (int s = 0; s < SEQ_LEN; ++s) {
        const float* hread = (s & 1) ? hbuf1 : hbuf0;
        float* hwrite      = (s & 1) ? hbuf0 : hbuf1;

        // stage h_s and x_s into LDS (coalesced 4KB + 256B)
        float4 hv = ((const float4*)hread)[t];
        hs4[t] = hv;
        if (t < 16) hs4[256 + t] = xin4[s * 16 + t];
        __syncthreads();

        // 64 FMAs vs W_hh + 4 vs W_ih, weights in VGPRs.
        float acc = 0.0f;
        #pragma unroll
        for (int c = 0; c < 16; ++c) {
            float4 h4 = hs4[16 * c + sl];
            acc = fmaf(wr[4 * c + 0], h4.x, acc);
            acc = fmaf(wr[4 * c + 1], h4.y, acc);
            acc = fmaf(wr[4 * c + 2], h4.z, acc);
            acc = fmaf(wr[4 * c + 3], h4.w, acc);
        }
        {
            float4 x4 = hs4[256 + sl];
            acc = fmaf(wr[64], x4.x, acc);
            acc = fmaf(wr[65], x4.y, acc);
            acc = fmaf(wr[66], x4.z, acc);
            acc = fmaf(wr[67], x4.w, acc);
        }

        // reduce across the 16 lanes of the gate group
        acc += __shfl_xor(acc, 1);
        acc += __shfl_xor(acc, 2);
        acc += __shfl_xor(acc, 4);
        acc += __shfl_xor(acc, 8);

        // gather the 4 gate preactivations (uniform within each group)
        float gi = __shfl(acc, 0)  + bias[0];
        float gf = __shfl(acc, 16) + bias[1];
        float gg = __shfl(acc, 32) + bias[2];
        float go = __shfl(acc, 48) + bias[3];

        float ig = fast_sigmoid(gi);
        float fg = fast_sigmoid(gf);
        float cg = fast_tanh(gg);
        float og = fast_sigmoid(go);
        c_state  = fmaf(fg, c_state, ig * cg);
        float hn = og * fast_tanh(c_state);

        if (l == 0) hwrite[j] = hn;   // one float per wave (16B per block, one line)
        __syncthreads();              // drains vmcnt(0): all 4 waves' h-stores in L2

        // ---- grid barrier: per-block flag (release) + all-poll-all + acquire fence
        if (t == 0)
            __hip_atomic_store(&flags[b], (unsigned)(s + 1),
                               __ATOMIC_RELEASE, __HIP_MEMORY_SCOPE_AGENT);
        if (t < 64) {
            const unsigned target = (unsigned)(s + 1);
            unsigned m;
            do {
                unsigned f0 = __hip_atomic_load(&flags[t      ], __ATOMIC_RELAXED, __HIP_MEMORY_SCOPE_AGENT);
                unsigned f1 = __hip_atomic_load(&flags[t +  64], __ATOMIC_RELAXED, __HIP_MEMORY_SCOPE_AGENT);
                unsigned f2 = __hip_atomic_load(&flags[t + 128], __ATOMIC_RELAXED, __HIP_MEMORY_SCOPE_AGENT);
                unsigned f3 = __hip_atomic_load(&flags[t + 192], __ATOMIC_RELAXED, __HIP_MEMORY_SCOPE_AGENT);
                m = umin4(f0, f1, f2, f3);
            } while (!__all(m >= target));
            // relaxed loads observed all release stores -> acquire fence synchronizes
            __scoped_atomic_thread_fence(__ATOMIC_ACQUIRE, __MEMORY_SCOPE_DEVICE);
        }
        __syncthreads();
    }

    // final projection: out = h_4096 . W_lin + b_lin  (h_4096 in hbuf0)
    if (b == 0) {
        float4 hv = ((const float4*)hbuf0)[t];
        float4 wl = ((const float4*)W_lin)[t];
        float p = hv.x * wl.x + hv.y * wl.y + hv.z * wl.z + hv.w * wl.w;
        #pragma unroll
        for (int m = 32; m >= 1; m >>= 1) p += __shfl_xor(p, m);
        if (l == 0) red[w] = p;
        __syncthreads();
        if (t == 0) out[0] = red[0] + red[1] + red[2] + red[3] + b_lin[0];
    }
}

extern "C" void kernel_launch(void* const* d_in, const int* in_sizes, int n_in,
                              void* d_out, int out_size, void* d_ws, size_t ws_size,
                              hipStream_t stream) {
    const float* input = (const float*)d_in[0];
    const float* W_ih  = (const float*)d_in[1];
    const float* W_hh  = (const float*)d_in[2];
    const float* b_ih  = (const float*)d_in[3];
    const float* b_hh  = (const float*)d_in[4];
    const float* W_lin = (const float*)d_in[5];
    const float* b_lin = (const float*)d_in[6];
    float* out = (float*)d_out;
    float* ws  = (float*)d_ws;

    hipLaunchKernelGGL(lstm_init_kernel, dim3(1), dim3(256), 0, stream, ws);

    void* args[] = { (void*)&input, (void*)&W_ih, (void*)&W_hh, (void*)&b_ih,
                     (void*)&b_hh, (void*)&W_lin, (void*)&b_lin, (void*)&out, (void*)&ws };
    (void)hipLaunchCooperativeKernel((void*)lstm_persistent_kernel, dim3(NBLK), dim3(TPB),
                                     args, 0, stream);
}